// Round 15
// baseline (216.336 us; speedup 1.0000x reference)
//
#include <hip/hip_runtime.h>
#include <math.h>

#define BB    4
#define TT    1024
#define DD    512
#define NH    8
#define DH    64
#define BH    32          // BB*NH
#define INV_TAU 10.0f

typedef __attribute__((ext_vector_type(8))) short short8;
typedef __attribute__((ext_vector_type(4))) float f4;
typedef __attribute__((ext_vector_type(8))) _Float16 half8;

__device__ inline unsigned short f2bf(float f) {
  unsigned u = __float_as_uint(f);
  u += 0x7FFFu + ((u >> 16) & 1u);        // round-to-nearest-even
  return (unsigned short)(u >> 16);
}
__device__ inline float bf2f(unsigned short h) {
  return __uint_as_float(((unsigned)h) << 16);
}
// Truncation split: pair error is only lo's rounding -> 1 op for hi.
__device__ inline unsigned short f2bf_t(float f) {
  return (unsigned short)(__float_as_uint(f) >> 16);
}

// pv work-item table: pair -> (ti<<2)|c, sorted heavy-first (len 4,3,2,1).
__device__ const unsigned char d_pvtbl[40] = {
  12, 16, 20, 24, 28, 29, 32, 33, 36, 37, 40, 41, 44, 45, 46, 48, 49, 50,
  52, 53, 54, 56, 57, 58, 60, 61, 62, 63,
  8, 25, 42, 59,
  4, 21, 38, 55,
  0, 17, 34, 51
};

// ---------------------------------------------------------------------------
// K0 "prep": merged split_x (blocks 0..2047) + split_wt (blocks 2048..2239).
// ---------------------------------------------------------------------------
__global__ __launch_bounds__(256) void k_prep(
    const float* __restrict__ x, const float* __restrict__ wq,
    const float* __restrict__ wk, const float* __restrict__ wv,
    unsigned short* __restrict__ xh, unsigned short* __restrict__ xl,
    unsigned short* __restrict__ wth, unsigned short* __restrict__ wtl)
{
  __shared__ float Wf[64][65];
  const int blk = blockIdx.x;
  const int tid = threadIdx.x;
  if (blk < 2048) {
    const int i = (blk * 256 + tid) * 4;
    float4 v = *(const float4*)&x[i];
    ushort4 h, l;
    h.x = f2bf_t(v.x); l.x = f2bf_t(v.x - bf2f(h.x));
    h.y = f2bf_t(v.y); l.y = f2bf_t(v.y - bf2f(h.y));
    h.z = f2bf_t(v.z); l.z = f2bf_t(v.z - bf2f(h.z));
    h.w = f2bf_t(v.w); l.w = f2bf_t(v.w - bf2f(h.w));
    *(ushort4*)&xh[i] = h;
    *(ushort4*)&xl[i] = l;
    return;
  }
  const int b = blk - 2048;                // 0..191
  const int ten = b >> 6;                  // 0..2
  const int r = b & 63;
  const int n0 = (r & 7) * 64, k0 = (r >> 3) * 64;
  const float* W = (ten == 0) ? wq : ((ten == 1) ? wk : wv);
#pragma unroll
  for (int p = 0; p < 4; ++p) {
    int kk = p * 16 + (tid >> 4);
    int nn = (tid & 15) * 4;
    float4 v = *(const float4*)&W[(size_t)(k0 + kk) * 512 + n0 + nn];
    Wf[kk][nn + 0] = v.x; Wf[kk][nn + 1] = v.y;
    Wf[kk][nn + 2] = v.z; Wf[kk][nn + 3] = v.w;
  }
  __syncthreads();
  const int n = tid >> 2, kq = tid & 3;
  size_t base = ((size_t)(ten * 512 + n0 + n)) * 512 + k0 + kq * 16;
#pragma unroll
  for (int jj = 0; jj < 4; ++jj) {
    ushort4 h, l;
    float f0 = Wf[kq * 16 + jj * 4 + 0][n];
    float f1 = Wf[kq * 16 + jj * 4 + 1][n];
    float f2 = Wf[kq * 16 + jj * 4 + 2][n];
    float f3 = Wf[kq * 16 + jj * 4 + 3][n];
    h.x = f2bf_t(f0); l.x = f2bf_t(f0 - bf2f(h.x));
    h.y = f2bf_t(f1); l.y = f2bf_t(f1 - bf2f(h.y));
    h.z = f2bf_t(f2); l.z = f2bf_t(f2 - bf2f(h.z));
    h.w = f2bf_t(f3); l.w = f2bf_t(f3 - bf2f(h.w));
    *(ushort4*)&wth[base + jj * 4] = h;
    *(ushort4*)&wtl[base + jj * 4] = l;
  }
}

// ---------------------------------------------------------------------------
// K1: QKV projection via bf16x3 MFMA + fused per-head softmax.
// ---------------------------------------------------------------------------
__global__ __launch_bounds__(256) void k_proj_mfma(
    const unsigned short* __restrict__ xh, const unsigned short* __restrict__ xl,
    const unsigned short* __restrict__ wth, const unsigned short* __restrict__ wtl,
    unsigned short* __restrict__ qh, unsigned short* __restrict__ ql,
    unsigned short* __restrict__ kh, unsigned short* __restrict__ kl,
    float* __restrict__ vs)
{
  __shared__ unsigned short Ah[64][40];
  __shared__ unsigned short Al[64][40];
  __shared__ unsigned short Bh[128][40];
  __shared__ unsigned short Bl[128][40];
  const int tid = threadIdx.x;
  const int n0g = blockIdx.x * 128;        // 0..1408
  const int m0 = blockIdx.y * 64;          // 0..4032
  const int w = tid >> 6, lane = tid & 63;
  const int mw = (w & 1) * 32, nw = (w >> 1) * 64;
  const int quad = lane >> 4, l16 = lane & 15;
  const int srow = tid >> 2;               // 0..63
  const int sk = (tid & 3) * 8;            // 0,8,16,24

  f4 acc[2][4] = {};

  for (int k0 = 0; k0 < DD; k0 += 32) {
    short8 a0 = *(const short8*)&xh[(size_t)(m0 + srow) * DD + k0 + sk];
    short8 a1 = *(const short8*)&xl[(size_t)(m0 + srow) * DD + k0 + sk];
    short8 b0 = *(const short8*)&wth[(size_t)(n0g + srow) * DD + k0 + sk];
    short8 b1 = *(const short8*)&wth[(size_t)(n0g + 64 + srow) * DD + k0 + sk];
    short8 b2 = *(const short8*)&wtl[(size_t)(n0g + srow) * DD + k0 + sk];
    short8 b3 = *(const short8*)&wtl[(size_t)(n0g + 64 + srow) * DD + k0 + sk];
    *(short8*)&Ah[srow][sk] = a0;
    *(short8*)&Al[srow][sk] = a1;
    *(short8*)&Bh[srow][sk] = b0;  *(short8*)&Bh[64 + srow][sk] = b1;
    *(short8*)&Bl[srow][sk] = b2;  *(short8*)&Bl[64 + srow][sk] = b3;
    __syncthreads();

    short8 fbh[4], fbl[4];
#pragma unroll
    for (int nt = 0; nt < 4; ++nt) {
      fbh[nt] = *(const short8*)&Bh[nw + nt * 16 + l16][quad * 8];
      fbl[nt] = *(const short8*)&Bl[nw + nt * 16 + l16][quad * 8];
    }
#pragma unroll
    for (int mt = 0; mt < 2; ++mt) {
      short8 fah = *(const short8*)&Ah[mw + mt * 16 + l16][quad * 8];
      short8 fal = *(const short8*)&Al[mw + mt * 16 + l16][quad * 8];
#pragma unroll
      for (int nt = 0; nt < 4; ++nt) {
        acc[mt][nt] = __builtin_amdgcn_mfma_f32_16x16x32_bf16(fah, fbh[nt], acc[mt][nt], 0, 0, 0);
        acc[mt][nt] = __builtin_amdgcn_mfma_f32_16x16x32_bf16(fah, fbl[nt], acc[mt][nt], 0, 0, 0);
        acc[mt][nt] = __builtin_amdgcn_mfma_f32_16x16x32_bf16(fal, fbh[nt], acc[mt][nt], 0, 0, 0);
      }
    }
    __syncthreads();
  }

  const int tensor = n0g >> 9;
  const int ncol = (n0g & 511) + nw;
  const int h = ncol >> 6;
#pragma unroll
  for (int mt = 0; mt < 2; ++mt) {
#pragma unroll
    for (int r = 0; r < 4; ++r) {
      float v0 = acc[mt][0][r], v1 = acc[mt][1][r];
      float v2 = acc[mt][2][r], v3 = acc[mt][3][r];
      float mx = fmaxf(fmaxf(v0, v1), fmaxf(v2, v3));
#pragma unroll
      for (int msk = 1; msk <= 8; msk <<= 1) mx = fmaxf(mx, __shfl_xor(mx, msk, 64));
      float e0 = __expf((v0 - mx) * INV_TAU);
      float e1 = __expf((v1 - mx) * INV_TAU);
      float e2 = __expf((v2 - mx) * INV_TAU);
      float e3 = __expf((v3 - mx) * INV_TAU);
      float sm = e0 + e1 + e2 + e3;
#pragma unroll
      for (int msk = 1; msk <= 8; msk <<= 1) sm += __shfl_xor(sm, msk, 64);
      float inv = 1.0f / sm;
      int row = m0 + mw + mt * 16 + quad * 4 + r;
      int b = row >> 10, t = row & 1023;
      size_t base = (((size_t)b * NH + h) * TT + t) * DH;
      float e[4] = {e0 * inv, e1 * inv, e2 * inv, e3 * inv};
      if (tensor == 2) {
#pragma unroll
        for (int c = 0; c < 4; ++c) vs[base + l16 + c * 16] = e[c];
      } else {
        unsigned short* oh = tensor ? kh : qh;
        unsigned short* ol = tensor ? kl : ql;
#pragma unroll
        for (int c = 0; c < 4; ++c) {
          unsigned short hh = f2bf_t(e[c]);
          oh[base + l16 + c * 16] = hh;
          ol[base + l16 + c * 16] = f2bf_t(e[c] - bf2f(hh));
        }
      }
    }
  }
}

// ---------------------------------------------------------------------------
// K2 "qkv": merged qk (blocks 0..1087) + vsplit (blocks 1088..1599).
// qk C-tile staged through LDS, half8 coalesced stores.
// ---------------------------------------------------------------------------
__global__ __launch_bounds__(256) void k_qkv(
    const unsigned short* __restrict__ qh, const unsigned short* __restrict__ ql,
    const unsigned short* __restrict__ kh, const unsigned short* __restrict__ kl,
    _Float16* __restrict__ A, const float* __restrict__ vs,
    unsigned short* __restrict__ vth, unsigned short* __restrict__ vtl)
{
  __shared__ char smem[4][32][68 * 2];     // 17.4 KB; vsplit aliases it
  const int tid = threadIdx.x;
  if (blockIdx.x >= 1088) {
    float (*Vf)[65] = (float(*)[65])smem;
    const int b = blockIdx.x - 1088;       // 0..511
    const int z = b & 31, t0 = (b >> 5) * 64;
#pragma unroll
    for (int it = 0; it < 4; ++it) {
      int tl = it * 16 + (tid >> 4);
      int d4 = (tid & 15) * 4;
      float4 v = *(const float4*)&vs[((size_t)z * TT + t0 + tl) * DH + d4];
      Vf[tl][d4 + 0] = v.x; Vf[tl][d4 + 1] = v.y;
      Vf[tl][d4 + 2] = v.z; Vf[tl][d4 + 3] = v.w;
    }
    __syncthreads();
#pragma unroll
    for (int it = 0; it < 8; ++it) {
      int d = it * 8 + (tid >> 5);
      int t = (tid & 31) * 2;
      float a0 = Vf[t][d], a1 = Vf[t + 1][d];
      unsigned short h0 = f2bf_t(a0), h1 = f2bf_t(a1);
      unsigned short l0 = f2bf_t(a0 - bf2f(h0)), l1 = f2bf_t(a1 - bf2f(h1));
      size_t o = ((size_t)z * DH + d) * TT + t0 + t;
      ushort2 hh; hh.x = h0; hh.y = h1;
      ushort2 ll; ll.x = l0; ll.y = l1;
      *(ushort2*)&vth[o] = hh;
      *(ushort2*)&vtl[o] = ll;
    }
    return;
  }
  const int gid = blockIdx.x * 4 + (tid >> 6);
  const int z = gid / 136;
  const int lx = gid - z * 136;
  int ti = (int)((sqrtf(8.0f * lx + 1.0f) - 1.0f) * 0.5f);
  while ((ti + 1) * (ti + 2) / 2 <= lx) ++ti;
  while (ti * (ti + 1) / 2 > lx) --ti;
  const int tj = lx - ti * (ti + 1) / 2;
  const int i0 = ti * 64, j0 = tj * 64;
  const int w = tid >> 6;
  const int lane = tid & 63;
  const int quad = lane >> 4, l16 = lane & 15;
  const size_t zb = (size_t)z * TT * DH;

  short8 fbh[4][2], fbl[4][2];
#pragma unroll
  for (int nt = 0; nt < 4; ++nt)
#pragma unroll
    for (int ks = 0; ks < 2; ++ks) {
      size_t o = zb + (size_t)(j0 + nt * 16 + l16) * DH + ks * 32 + quad * 8;
      fbh[nt][ks] = *(const short8*)&kh[o];
      fbl[nt][ks] = *(const short8*)&kl[o];
    }

  f4 acc[4][4] = {};
#pragma unroll
  for (int mt = 0; mt < 4; ++mt) {
    short8 fah[2], fal[2];
#pragma unroll
    for (int ks = 0; ks < 2; ++ks) {
      size_t o = zb + (size_t)(i0 + mt * 16 + l16) * DH + ks * 32 + quad * 8;
      fah[ks] = *(const short8*)&qh[o];
      fal[ks] = *(const short8*)&ql[o];
    }
#pragma unroll
    for (int nt = 0; nt < 4; ++nt)
#pragma unroll
      for (int ks = 0; ks < 2; ++ks) {
        acc[mt][nt] = __builtin_amdgcn_mfma_f32_16x16x32_bf16(fah[ks], fbh[nt][ks], acc[mt][nt], 0, 0, 0);
        acc[mt][nt] = __builtin_amdgcn_mfma_f32_16x16x32_bf16(fah[ks], fbl[nt][ks], acc[mt][nt], 0, 0, 0);
        acc[mt][nt] = __builtin_amdgcn_mfma_f32_16x16x32_bf16(fal[ks], fbh[nt][ks], acc[mt][nt], 0, 0, 0);
      }
  }

  _Float16* Ab = A + (size_t)z * TT * TT;
  _Float16 (*Ts)[68] = (_Float16(*)[68])smem[w];
#pragma unroll
  for (int round = 0; round < 2; ++round) {
#pragma unroll
    for (int m2 = 0; m2 < 2; ++m2) {
      int mt = round * 2 + m2;
#pragma unroll
      for (int nt = 0; nt < 4; ++nt)
#pragma unroll
        for (int r = 0; r < 4; ++r)
          Ts[m2 * 16 + quad * 4 + r][nt * 16 + l16] = (_Float16)acc[mt][nt][r];
    }
    const int rrow = lane >> 3, seg = (lane & 7) * 8;
#pragma unroll
    for (int r2 = 0; r2 < 4; ++r2) {
      int row = rrow + 8 * r2;
      half8 v = *(const half8*)&Ts[row][seg];
      *(half8*)&Ab[(size_t)(i0 + round * 32 + row) * TT + j0 + seg] = v;
    }
  }
}

// ---------------------------------------------------------------------------
// K3: diagonal run-length scan — 3-pass, fp16 I/O, fp32 math.
// ---------------------------------------------------------------------------
__global__ __launch_bounds__(1024) void k_scan(_Float16* __restrict__ A)
{
  __shared__ float Ssum[16][64];
  __shared__ float Gmax[16][64];
  const int blk = blockIdx.x;              // 0..511
  const int p = blk >> 5;                  // 0..15
  const int xb = (p < 8) ? p : (23 - p);   // complementary pairing across CUs
  const int z = blk & 31;
  const int lane = threadIdx.x & 63;
  const int w = threadIdx.x >> 6;          // chunk 0..15
  _Float16* __restrict__ Ab = A + (size_t)z * TT * TT;
  const int dbase = xb * 64;
  const int d = dbase + lane;
  const int L = (TT - dbase) >> 4;         // 4..64 rows per chunk
  const int r0 = dbase + w * L;

  float S = 0.0f;
#pragma unroll 8
  for (int t = 0; t < L; ++t) {
    int i = r0 + t;
    size_t idx = (i >= d) ? ((size_t)i * (TT + 1) - d) : 0;
    float s = (float)Ab[idx];
    S += (i >= d) ? s : 0.0f;
  }
  Ssum[w][lane] = S;
  __syncthreads();

  float cs_in = 0.0f;
  for (int ww = 0; ww < w; ++ww) cs_in += Ssum[ww][lane];

  {
    float lcs = 0.0f, gm = 0.0f;
#pragma unroll 8
    for (int t = 0; t < L; ++t) {
      int i = r0 + t;
      size_t idx = (i >= d) ? ((size_t)i * (TT + 1) - d) : 0;
      float s0 = (float)Ab[idx];
      float s = (i >= d) ? s0 : 0.0f;
      lcs += s;
      gm = fmaxf(gm, (cs_in + lcs) * (1.0f - s));
    }
    Gmax[w][lane] = gm;
  }
  __syncthreads();

  float m = 0.0f;
  for (int ww = 0; ww < w; ++ww) m = fmaxf(m, Gmax[ww][lane]);

  {
    float lcs = 0.0f;
#pragma unroll 8
    for (int t = 0; t < L; ++t) {
      int i = r0 + t;
      bool ok = (i >= d);
      size_t idx = ok ? ((size_t)i * (TT + 1) - d) : 0;
      float s0 = (float)Ab[idx];
      float s = ok ? s0 : 0.0f;
      lcs += s;
      float cs = cs_in + lcs;
      m = fmaxf(m, cs * (1.0f - s));
      if (ok) Ab[idx] = (_Float16)(cs - m);
    }
  }
}

// ---------------------------------------------------------------------------
// K4: softmax(P)·V, fine split-K (chunks of <=4 jt). Two-pass per chunk:
// all scores loaded -> single max -> exp+pack+MFMA (no online rescale, no
// per-step cross-lane ops). Every chunk emits an unnormalized partial
// (Opart + per-row m,l); combine fused in k_oproj. 5120 one-wave blocks,
// heavy-first table -> ~68 balanced jt-units per CU at 20 items/CU.
// ---------------------------------------------------------------------------
__global__ __launch_bounds__(64) void k_pv(
    const _Float16* __restrict__ A, const unsigned short* __restrict__ vth,
    const unsigned short* __restrict__ vtl,
    float* __restrict__ Opart, float* __restrict__ ml)
{
  const int lane = threadIdx.x;
  const int quad = lane >> 4, l16 = lane & 15;
  const int blk = blockIdx.x;              // 0..5119
  const int z = blk & 31;
  const int item = blk >> 5;               // 0..159
  const int code = d_pvtbl[item >> 2];
  const int band = item & 3;
  const int ti = code >> 2, c = code & 3;
  const int jt0 = c * 4;
  const int nst = min(ti + 1 - jt0, 4);    // 1..4, wave-uniform

  const _Float16* Az = A + (size_t)z * TT * TT;
  const unsigned short* vh = vth + (size_t)z * DH * TT;
  const unsigned short* vl = vtl + (size_t)z * DH * TT;

  const int i0 = ti * 64;
  const int irow = i0 + band * 16 + l16;   // this lane's P-row
  const float invi = 1.0f / (float)(irow + 1);

  float posu[16];
#pragma unroll
  for (int u = 0; u < 16; ++u)
    posu[u] = (float)((u >> 3) * 32 + quad * 8 + (u & 7)) * invi;

  // Pass 1: load all scores, add pos, mask diagonal step, chunk max.
  float sc[4][16];
  float mx = -3e38f;
#pragma unroll
  for (int st = 0; st < 4; ++st) {
    if (st < nst) {
      const int jt = jt0 + st;
      const bool masked = (jt == ti);
      const float jtoff = (float)(jt * 64) * invi;
#pragma unroll
      for (int ks = 0; ks < 2; ++ks) {
        half8 hv = *(const half8*)&Az[(size_t)irow * TT + jt * 64 + ks * 32 + quad * 8];
#pragma unroll
        for (int u = 0; u < 8; ++u) sc[st][ks * 8 + u] = (float)hv[u];
      }
#pragma unroll
      for (int u = 0; u < 16; ++u) {
        float v = sc[st][u] + (jtoff + posu[u]);
        int j = jt * 64 + (u >> 3) * 32 + quad * 8 + (u & 7);
        sc[st][u] = (masked && j > irow) ? -3e38f : v;
        mx = fmaxf(mx, sc[st][u]);
      }
    }
  }
  mx = fmaxf(mx, __shfl_xor(mx, 16, 64));
  mx = fmaxf(mx, __shfl_xor(mx, 32, 64));   // row max, replicated

  // Pass 2: exp + pack + MFMA (independent accumulation, no rescale).
  f4 acc[4] = {};
  float ls = 0.0f;
#pragma unroll
  for (int st = 0; st < 4; ++st) {
    if (st < nst) {
      const int jt = jt0 + st;
#pragma unroll
      for (int ks = 0; ks < 2; ++ks) {
        short8 pah, pal;
#pragma unroll
        for (int u = 0; u < 8; ++u) {
          float pvv = __expf((sc[st][ks * 8 + u] - mx) * INV_TAU);
          ls += pvv;
          unsigned short hh = f2bf_t(pvv);
          pah[u] = (short)hh;
          pal[u] = (short)f2bf_t(pvv - bf2f(hh));
        }
#pragma unroll
        for (int nt = 0; nt < 4; ++nt) {
          size_t vo = (size_t)(nt * 16 + l16) * TT + jt * 64 + ks * 32 + quad * 8;
          short8 fvh = *(const short8*)&vh[vo];
          short8 fvl = *(const short8*)&vl[vo];
          acc[nt] = __builtin_amdgcn_mfma_f32_16x16x32_bf16(pah, fvh, acc[nt], 0, 0, 0);
          acc[nt] = __builtin_amdgcn_mfma_f32_16x16x32_bf16(pah, fvl, acc[nt], 0, 0, 0);
          acc[nt] = __builtin_amdgcn_mfma_f32_16x16x32_bf16(pal, fvh, acc[nt], 0, 0, 0);
        }
      }
    }
  }
  ls += __shfl_xor(ls, 16, 64);
  ls += __shfl_xor(ls, 32, 64);            // row sum, replicated

  if (quad == 0) {
    size_t mo = (((size_t)c * 32 + z) * TT + irow) * 2;
    ml[mo + 0] = mx;
    ml[mo + 1] = ls;
  }
#pragma unroll
  for (int rr = 0; rr < 4; ++rr) {
    int orow = i0 + band * 16 + quad * 4 + rr;
    size_t po = (((size_t)c * 32 + z) * TT + orow) * 64;
#pragma unroll
    for (int nt = 0; nt < 4; ++nt)
      Opart[po + nt * 16 + l16] = acc[nt][rr];
  }
}

// ---------------------------------------------------------------------------
// K6: per-head output projection + fused split-K combine (<=4 partials/row).
// ---------------------------------------------------------------------------
__global__ __launch_bounds__(256) void k_oproj(
    const float* __restrict__ wo, const float* __restrict__ Opart,
    const float* __restrict__ ml, float* __restrict__ out)
{
  __shared__ float Wl[64][64];
  __shared__ float Ol[16][64];
  const int z = blockIdx.y;                // b*NH + h
  const int t0 = blockIdx.x * 16;
  const int b = z >> 3, h = z & 7;
  const int tid = threadIdx.x;
  const float* wb = wo + (size_t)h * 64 * 64;
#pragma unroll
  for (int u = 0; u < 4; ++u) {
    int q = tid + 256 * u;
    int dd = q >> 4, e4 = (q & 15) * 4;
    *(float4*)&Wl[dd][e4] = *(const float4*)&wb[(size_t)dd * 64 + e4];
  }
  {
    int rr = tid >> 4, d4 = (tid & 15) * 4;
    int trow = t0 + rr;
    int ti = trow >> 6;
    int nc = (ti >> 2) + 1;                // 1..4 partials
    float mv[4], lv[4];
    float mm = -3e38f;
#pragma unroll
    for (int c = 0; c < 4; ++c) {
      if (c < nc) {
        size_t mo = (((size_t)c * 32 + z) * TT + trow) * 2;
        mv[c] = ml[mo]; lv[c] = ml[mo + 1];
        mm = fmaxf(mm, mv[c]);
      }
    }
    float den = 0.0f;
    float o0 = 0.0f, o1 = 0.0f, o2 = 0.0f, o3 = 0.0f;
#pragma unroll
    for (int c = 0; c < 4; ++c) {
      if (c < nc) {
        float wgt = __expf((mv[c] - mm) * INV_TAU);
        den += lv[c] * wgt;
        float4 oc = *(const float4*)&Opart[(((size_t)c * 32 + z) * TT + trow) * 64 + d4];
        o0 += oc.x * wgt; o1 += oc.y * wgt; o2 += oc.z * wgt; o3 += oc.w * wgt;
      }
    }
    float inv = 1.0f / den;
    Ol[rr][d4 + 0] = o0 * inv;
    Ol[rr][d4 + 1] = o1 * inv;
    Ol[rr][d4 + 2] = o2 * inv;
    Ol[rr][d4 + 3] = o3 * inv;
  }
  __syncthreads();
  const int rg = tid >> 6, e = tid & 63;
  float a0 = 0, a1 = 0, a2 = 0, a3 = 0;
#pragma unroll
  for (int dd = 0; dd < 64; ++dd) {
    float wv = Wl[dd][e];
    a0 += Ol[rg * 4 + 0][dd] * wv;
    a1 += Ol[rg * 4 + 1][dd] * wv;
    a2 += Ol[rg * 4 + 2][dd] * wv;
    a3 += Ol[rg * 4 + 3][dd] * wv;
  }
  size_t ob = ((size_t)b * TT + t0 + rg * 4) * DD + h * 64 + e;
  out[ob] = a0; out[ob + DD] = a1; out[ob + 2 * DD] = a2; out[ob + 3 * DD] = a3;
}

// ---------------------------------------------------------------------------
// ws layout (<=164 MB):
//  [0,4) qh  [4,8) ql  [8,12) kh  [12,16) kl
//  [16,24) vs fp32   [24,28) vth  [28,32) vtl
//  [33,97) A fp16    ([33,41) doubles as xh/xl before k_qkv overwrites it)
//  [97,129) Opart (4 chunks x 32 z x 1024 x 64 fp32 = 32 MB)
//  [129,130) ml (4 x 32 x 1024 x 2 fp32 = 1 MB)
//  [161,162.5) wth   [162.5,164) wtl
// ---------------------------------------------------------------------------
extern "C" void kernel_launch(void* const* d_in, const int* in_sizes, int n_in,
                              void* d_out, int out_size, void* d_ws, size_t ws_size,
                              hipStream_t stream)
{
  (void)in_sizes; (void)n_in; (void)out_size; (void)ws_size;
  const float* x  = (const float*)d_in[0];
  const float* wq = (const float*)d_in[1];
  const float* wk = (const float*)d_in[2];
  const float* wv = (const float*)d_in[3];
  const float* wo = (const float*)d_in[4];
  float* out = (float*)d_out;

  char* ws = (char*)d_ws;
  const size_t MB = 1024 * 1024;
  unsigned short* qh = (unsigned short*)(ws);
  unsigned short* ql = (unsigned short*)(ws + 4 * MB);
  unsigned short* kh = (unsigned short*)(ws + 8 * MB);
  unsigned short* kl = (unsigned short*)(ws + 12 * MB);
  float*          vs = (float*)(ws + 16 * MB);
  unsigned short* vth = (unsigned short*)(ws + 24 * MB);
  unsigned short* vtl = (unsigned short*)(ws + 28 * MB);
  _Float16*       A  = (_Float16*)(ws + 33 * MB);
  unsigned short* xh = (unsigned short*)(ws + 33 * MB);   // aliases A (dead by k_qkv)
  unsigned short* xl = (unsigned short*)(ws + 37 * MB);
  float*          Opart = (float*)(ws + 97 * MB);
  float*          ml = (float*)(ws + 129 * MB);
  unsigned short* wth = (unsigned short*)(ws + 161 * MB);
  unsigned short* wtl = (unsigned short*)(ws + 161 * MB + 1536 * 1024);

  hipLaunchKernelGGL(k_prep, dim3(2048 + 192), dim3(256), 0, stream,
                     x, wq, wk, wv, xh, xl, wth, wtl);
  hipLaunchKernelGGL(k_proj_mfma, dim3(12, 64), dim3(256), 0, stream,
                     xh, xl, wth, wtl, qh, ql, kh, kl, vs);
  hipLaunchKernelGGL(k_qkv, dim3(1088 + 512), dim3(256), 0, stream,
                     qh, ql, kh, kl, A, vs, vth, vtl);
  hipLaunchKernelGGL(k_scan, dim3(512), dim3(1024), 0, stream, A);
  hipLaunchKernelGGL(k_pv, dim3(5120), dim3(64), 0, stream, A, vth, vtl,
                     Opart, ml);
  hipLaunchKernelGGL(k_oproj, dim3(64, 32), dim3(256), 0, stream,
                     wo, Opart, ml, out);
}